// Round 5
// baseline (764.891 us; speedup 1.0000x reference)
//
#include <hip/hip_runtime.h>
#include <hip/hip_bf16.h>

#define H 128
#define DOUT 32
#define NGRAPH 64
#define MM_ROWS 64
#define SORT_TILE 4096
#define NBUCK_MAX 128

// bf16 helpers (RTN-even pack, bit-shift unpack)
static __device__ __forceinline__ unsigned short f2bf(float v) {
    unsigned int u = __float_as_uint(v);
    unsigned int r = (u + 0x7FFFu + ((u >> 16) & 1u)) >> 16;
    return (unsigned short)r;
}
#define BFLO(w) __uint_as_float((w) << 16)
#define BFHI(w) __uint_as_float((w) & 0xFFFF0000u)

// ---------------- edge bucket sort (by dst >> bshift) ----------------

__global__ __launch_bounds__(256) void bucket_hist_kernel(const int* __restrict__ dst, int E,
                                                          int bshift, int* __restrict__ bcnt) {
    __shared__ int lh[NBUCK_MAX];
    int t = threadIdx.x;
    if (t < NBUCK_MAX) lh[t] = 0;
    __syncthreads();
    int base = blockIdx.x * SORT_TILE;
    int cnt = E - base;
    if (cnt > SORT_TILE) cnt = SORT_TILE;
    for (int j = t; j < cnt; j += 256) atomicAdd(&lh[dst[base + j] >> bshift], 1);
    __syncthreads();
    if (t < NBUCK_MAX && lh[t]) atomicAdd(&bcnt[t], lh[t]);
}

__global__ void bucket_scan_kernel(const int* __restrict__ bcnt, int* __restrict__ bfill,
                                   int nbuck) {
    if (threadIdx.x == 0) {
        int run = 0;
        for (int b = 0; b < nbuck; ++b) {
            bfill[b] = run;
            run += bcnt[b];
        }
    }
}

__global__ __launch_bounds__(256) void bucket_scatter_kernel(const int* __restrict__ src,
                                                             const int* __restrict__ dst, int E,
                                                             int bshift, int* __restrict__ bfill,
                                                             int2* __restrict__ es) {
    __shared__ int lh[NBUCK_MAX], lsc[NBUCK_MAX], lbase[NBUCK_MAX], lfill[NBUCK_MAX],
        ldelta[NBUCK_MAX];
    __shared__ int2 sp[SORT_TILE];
    __shared__ unsigned char sb[SORT_TILE];
    int t = threadIdx.x;
    if (t < NBUCK_MAX) {
        lh[t] = 0;
        lfill[t] = 0;
    }
    __syncthreads();
    int base = blockIdx.x * SORT_TILE;
    int cnt = E - base;
    if (cnt > SORT_TILE) cnt = SORT_TILE;
    for (int j = t; j < cnt; j += 256) atomicAdd(&lh[dst[base + j] >> bshift], 1);
    __syncthreads();
    if (t < NBUCK_MAX) lsc[t] = lh[t];
    __syncthreads();
    for (int off = 1; off < NBUCK_MAX; off <<= 1) {
        int x = 0;
        if (t < NBUCK_MAX && t >= off) x = lsc[t - off];
        __syncthreads();
        if (t < NBUCK_MAX) lsc[t] += x;
        __syncthreads();
    }
    if (t < NBUCK_MAX) {
        lbase[t] = lsc[t] - lh[t];
        if (lh[t] > 0) ldelta[t] = atomicAdd(&bfill[t], lh[t]) - lbase[t];
    }
    __syncthreads();
    for (int j = t; j < cnt; j += 256) {
        int s = src[base + j], d = dst[base + j];
        int b = d >> bshift;
        int r = atomicAdd(&lfill[b], 1);
        int slot = lbase[b] + r;
        sp[slot] = make_int2(s, d);
        sb[slot] = (unsigned char)b;
    }
    __syncthreads();
    for (int j = t; j < cnt; j += 256) {
        int b = sb[j];
        es[ldelta[b] + j] = sp[j];
    }
}

__global__ __launch_bounds__(256) void deg_hist_sorted(const int2* __restrict__ es, int E,
                                                       int* __restrict__ deg) {
    int e = blockIdx.x * 256 + threadIdx.x;
    if (e < E) atomicAdd(&deg[es[e].y], 1);
}

__global__ __launch_bounds__(256) void fill_csr_sorted(const int2* __restrict__ es, int E,
                                                       int* __restrict__ fill,
                                                       int* __restrict__ col) {
    int e = blockIdx.x * 256 + threadIdx.x;
    if (e < E) {
        int2 p = es[e];
        int pos = atomicAdd(&fill[p.y], 1);
        col[pos] = p.x;
    }
}

// ---------------- CSR row_ptr scan / misc ----------------

__global__ __launch_bounds__(256) void batch_bounds_kernel(const int* __restrict__ batch,
                                                           int N, int* __restrict__ gstart) {
    int i = blockIdx.x * 256 + threadIdx.x;
    if (i < N) {
        int b = batch[i];
        int bp = (i == 0) ? -1 : batch[i - 1];
        for (int g = bp + 1; g <= b; ++g) gstart[g] = i;
        if (i == N - 1)
            for (int g = b + 1; g <= NGRAPH; ++g) gstart[g] = N;
    }
}

__global__ __launch_bounds__(256) void scan_phase1(const int* __restrict__ deg, int N,
                                                   int* __restrict__ bsum) {
    __shared__ int sd[256];
    int t = threadIdx.x;
    int base = blockIdx.x * 1024 + t * 4;
    int s = 0;
#pragma unroll
    for (int j = 0; j < 4; ++j)
        if (base + j < N) s += deg[base + j];
    sd[t] = s;
    __syncthreads();
    for (int off = 128; off > 0; off >>= 1) {
        if (t < off) sd[t] += sd[t + off];
        __syncthreads();
    }
    if (t == 0) bsum[blockIdx.x] = sd[0];
}

__global__ void scan_phase2(int* bsum, int nb, int* __restrict__ row_ptr, int N, int E) {
    if (threadIdx.x == 0) {
        int run = 0;
        for (int i = 0; i < nb; ++i) {
            int v = bsum[i];
            bsum[i] = run;
            run += v;
        }
        row_ptr[N] = E;
    }
}

__global__ __launch_bounds__(256) void scan_phase3(const int* __restrict__ deg,
                                                   const int* __restrict__ boff, int N,
                                                   int* __restrict__ row_ptr) {
    __shared__ int sd[256];
    int t = threadIdx.x;
    int base = blockIdx.x * 1024 + t * 4;
    int v[4];
    int s = 0;
#pragma unroll
    for (int j = 0; j < 4; ++j) {
        v[j] = (base + j < N) ? deg[base + j] : 0;
        s += v[j];
    }
    sd[t] = s;
    __syncthreads();
    for (int off = 1; off < 256; off <<= 1) {
        int x = (t >= off) ? sd[t - off] : 0;
        __syncthreads();
        sd[t] += x;
        __syncthreads();
    }
    int run = boff[blockIdx.x] + sd[t] - s;
#pragma unroll
    for (int j = 0; j < 4; ++j)
        if (base + j < N) {
            row_ptr[base + j] = run;
            run += v[j];
        }
}

__global__ __launch_bounds__(256) void init_node_kernel(const int* __restrict__ deg,
                                                        const int* __restrict__ row_ptr,
                                                        float* __restrict__ dinv,
                                                        int* __restrict__ fill, int N) {
    int i = blockIdx.x * 256 + threadIdx.x;
    if (i < N) {
        dinv[i] = rsqrtf(1.0f + (float)deg[i]);
        fill[i] = row_ptr[i];
    }
}

// ---------------- compute ----------------

// Out_bf[row] = bf16((X[row] @ W) * dinv[row]);  X:[M,128] fp32, W:[128,128]
__global__ __launch_bounds__(256) void mm_scale_kernel(const float* __restrict__ X,
                                                       const float* __restrict__ W,
                                                       const float* __restrict__ dinv,
                                                       unsigned short* __restrict__ Out, int M) {
    __shared__ float xs[128 * 65];
    int tid = threadIdx.x;
    int row0 = blockIdx.x * MM_ROWS;
    int c = tid & 31, rl = tid >> 5;
#pragma unroll
    for (int p = 0; p < MM_ROWS; p += 8) {
        int m = p + rl;
        int row = row0 + m;
        float4 v = make_float4(0.f, 0.f, 0.f, 0.f);
        if (row < M) v = *reinterpret_cast<const float4*>(X + (size_t)row * H + c * 4);
        xs[(4 * c + 0) * 65 + m] = v.x;
        xs[(4 * c + 1) * 65 + m] = v.y;
        xs[(4 * c + 2) * 65 + m] = v.z;
        xs[(4 * c + 3) * 65 + m] = v.w;
    }
    __syncthreads();
    int tx = tid & 31;
    int ty = tid >> 5;
    float acc[8][4];
#pragma unroll
    for (int i = 0; i < 8; ++i)
#pragma unroll
        for (int j = 0; j < 4; ++j) acc[i][j] = 0.f;
#pragma unroll 4
    for (int k = 0; k < 128; ++k) {
        float4 w = *reinterpret_cast<const float4*>(W + k * H + tx * 4);
        float xv[8];
#pragma unroll
        for (int i = 0; i < 8; ++i) xv[i] = xs[k * 65 + ty * 8 + i];
#pragma unroll
        for (int i = 0; i < 8; ++i) {
            acc[i][0] = fmaf(xv[i], w.x, acc[i][0]);
            acc[i][1] = fmaf(xv[i], w.y, acc[i][1]);
            acc[i][2] = fmaf(xv[i], w.z, acc[i][2]);
            acc[i][3] = fmaf(xv[i], w.w, acc[i][3]);
        }
    }
#pragma unroll
    for (int i = 0; i < 8; ++i) {
        int row = row0 + ty * 8 + i;
        if (row < M) {
            float sc = dinv[row];
            unsigned int u0 = (unsigned int)f2bf(acc[i][0] * sc) |
                              ((unsigned int)f2bf(acc[i][1] * sc) << 16);
            unsigned int u1 = (unsigned int)f2bf(acc[i][2] * sc) |
                              ((unsigned int)f2bf(acc[i][3] * sc) << 16);
            *reinterpret_cast<uint2*>(Out + (size_t)row * H + tx * 4) = make_uint2(u0, u1);
        }
    }
}

// One wave per dst row; lane owns features {2*lane, 2*lane+1} (one u32 = 2 bf16).
// FUSE=0: Out[i] = relu(dinv*(sum+self)+bias)  (fp32)
// FUSE=1: atomicAdd the relu'd row into gsum[batch[i]*H + f]  (pool fusion)
template <int FUSE>
__global__ __launch_bounds__(256) void agg_bf16_kernel(
    const unsigned int* __restrict__ Au, const int* __restrict__ row_ptr,
    const int* __restrict__ col, const float* __restrict__ dinv,
    const float* __restrict__ bias, const int* __restrict__ batch,
    float* __restrict__ Out, float* __restrict__ gsum, int N) {
    int wave = threadIdx.x >> 6;
    int lane = threadIdx.x & 63;
    int i = blockIdx.x * 4 + wave;
    if (i >= N) return;
    int s = row_ptr[i], e = row_ptr[i + 1];
    unsigned int ws = Au[(size_t)i * 64 + lane];  // self-loop term
    float acc0 = BFLO(ws), acc1 = BFHI(ws);
    int j = s;
    for (; j + 4 <= e; j += 4) {
        int c0 = col[j], c1 = col[j + 1], c2 = col[j + 2], c3 = col[j + 3];
        unsigned int w0 = Au[(size_t)c0 * 64 + lane];
        unsigned int w1 = Au[(size_t)c1 * 64 + lane];
        unsigned int w2 = Au[(size_t)c2 * 64 + lane];
        unsigned int w3 = Au[(size_t)c3 * 64 + lane];
        acc0 += BFLO(w0) + BFLO(w1);
        acc1 += BFHI(w0) + BFHI(w1);
        acc0 += BFLO(w2) + BFLO(w3);
        acc1 += BFHI(w2) + BFHI(w3);
    }
    for (; j < e; ++j) {
        unsigned int w = Au[(size_t)col[j] * 64 + lane];
        acc0 += BFLO(w);
        acc1 += BFHI(w);
    }
    float d = dinv[i];
    float o0 = fmaxf(fmaf(d, acc0, bias[2 * lane]), 0.f);
    float o1 = fmaxf(fmaf(d, acc1, bias[2 * lane + 1]), 0.f);
    if (FUSE) {
        int g = batch[i];
        atomicAdd(&gsum[g * H + 2 * lane], o0);
        atomicAdd(&gsum[g * H + 2 * lane + 1], o1);
    } else {
        *reinterpret_cast<float2*>(Out + (size_t)i * H + 2 * lane) = make_float2(o0, o1);
    }
}

__global__ __launch_bounds__(128) void pool_final(const float* __restrict__ gsum,
                                                  const int* __restrict__ gstart,
                                                  float* __restrict__ g) {
    int gr = blockIdx.x, f = threadIdx.x;
    int cnt = gstart[gr + 1] - gstart[gr];
    g[gr * H + f] = gsum[gr * H + f] / fmaxf((float)cnt, 1.f);
}

__global__ __launch_bounds__(128) void head_kernel(const float* __restrict__ g,
                                                   const float* __restrict__ fW1,
                                                   const float* __restrict__ fb1,
                                                   const float* __restrict__ fW2,
                                                   const float* __restrict__ fb2,
                                                   float* __restrict__ out) {
    __shared__ float gv[H], hid[H], lg[DOUT];
    int gr = blockIdx.x, f = threadIdx.x;
    gv[f] = g[gr * H + f];
    __syncthreads();
    float acc = fb1[f];
    for (int k = 0; k < H; ++k) acc = fmaf(gv[k], fW1[k * H + f], acc);
    hid[f] = fmaxf(acc, 0.f);
    __syncthreads();
    if (f < DOUT) {
        float a = fb2[f];
        for (int k = 0; k < H; ++k) a = fmaf(hid[k], fW2[k * DOUT + f], a);
        lg[f] = a;
    }
    __syncthreads();
    if (f < DOUT) {
        float mx = -1e30f;
        for (int j = 0; j < DOUT; ++j) mx = fmaxf(mx, lg[j]);
        float ssum = 0.f;
        for (int j = 0; j < DOUT; ++j) ssum += expf(lg[j] - mx);
        out[gr * DOUT + f] = expf(lg[f] - mx) / ssum;
    }
}

// ---------------- launch ----------------

extern "C" void kernel_launch(void* const* d_in, const int* in_sizes, int n_in,
                              void* d_out, int out_size, void* d_ws, size_t ws_size,
                              hipStream_t stream) {
    const float* x = (const float*)d_in[0];
    const int* edge = (const int*)d_in[1];
    const int* batch = (const int*)d_in[2];
    const float* W1 = (const float*)d_in[3];
    const float* b1 = (const float*)d_in[4];
    const float* W2 = (const float*)d_in[5];
    const float* b2 = (const float*)d_in[6];
    const float* fW1 = (const float*)d_in[7];
    const float* fb1 = (const float*)d_in[8];
    const float* fW2 = (const float*)d_in[9];
    const float* fb2 = (const float*)d_in[10];
    float* out = (float*)d_out;

    int N = in_sizes[0] / H;
    int E = in_sizes[1] / 2;
    const int* srcI = edge;
    const int* dstI = edge + E;

    char* ws = (char*)d_ws;
    size_t off = 0;
    auto alloc = [&](size_t bytes) {
        void* p = ws + off;
        off = (off + bytes + 255) & ~(size_t)255;
        return p;
    };
    int* deg = (int*)alloc((size_t)N * 4);
    int* row_ptr = (int*)alloc((size_t)(N + 1) * 4);
    int* fill = (int*)alloc((size_t)N * 4);
    int* col = (int*)alloc((size_t)E * 4);
    float* dinv = (float*)alloc((size_t)N * 4);
    int* bsum = (int*)alloc(4096);
    int* gstart = (int*)alloc(512);
    int* bcnt = (int*)alloc(NBUCK_MAX * 4);
    int* bfill = (int*)alloc(NBUCK_MAX * 4);
    float* gsum = (float*)alloc((size_t)NGRAPH * H * 4);
    float* gmat = (float*)alloc((size_t)NGRAPH * H * 4);
    // A region: holds es (E*8B) during CSR build, then bf16 activations (N*H*2B)
    unsigned short* Abf = (unsigned short*)alloc((size_t)N * H * 4);
    float* Bm = (float*)alloc((size_t)N * H * 4);
    (void)ws_size;

    int2* es = (int2*)Abf;  // consumed before mm_scale overwrites; same stream

    int bshift = 0;
    while (((N - 1) >> bshift) >= NBUCK_MAX) ++bshift;
    int nbuck = ((N - 1) >> bshift) + 1;

    hipMemsetAsync(deg, 0, (size_t)N * 4, stream);
    hipMemsetAsync(bcnt, 0, NBUCK_MAX * 4, stream);
    hipMemsetAsync(gsum, 0, (size_t)NGRAPH * H * 4, stream);

    int nb = (N + 1023) / 1024;
    int nst = (E + SORT_TILE - 1) / SORT_TILE;

    bucket_hist_kernel<<<nst, 256, 0, stream>>>(dstI, E, bshift, bcnt);
    bucket_scan_kernel<<<1, 1, 0, stream>>>(bcnt, bfill, nbuck);
    bucket_scatter_kernel<<<nst, 256, 0, stream>>>(srcI, dstI, E, bshift, bfill, es);
    deg_hist_sorted<<<(E + 255) / 256, 256, 0, stream>>>(es, E, deg);

    batch_bounds_kernel<<<(N + 255) / 256, 256, 0, stream>>>(batch, N, gstart);
    scan_phase1<<<nb, 256, 0, stream>>>(deg, N, bsum);
    scan_phase2<<<1, 1, 0, stream>>>(bsum, nb, row_ptr, N, E);
    scan_phase3<<<nb, 256, 0, stream>>>(deg, bsum, N, row_ptr);
    init_node_kernel<<<(N + 255) / 256, 256, 0, stream>>>(deg, row_ptr, dinv, fill, N);
    fill_csr_sorted<<<(E + 255) / 256, 256, 0, stream>>>(es, E, fill, col);

    int mmblocks = (N + MM_ROWS - 1) / MM_ROWS;
    int aggblocks = (N + 3) / 4;
    mm_scale_kernel<<<mmblocks, 256, 0, stream>>>(x, W1, dinv, Abf, N);
    agg_bf16_kernel<0><<<aggblocks, 256, 0, stream>>>((const unsigned int*)Abf, row_ptr, col,
                                                      dinv, b1, batch, Bm, gsum, N);
    mm_scale_kernel<<<mmblocks, 256, 0, stream>>>(Bm, W2, dinv, Abf, N);
    agg_bf16_kernel<1><<<aggblocks, 256, 0, stream>>>((const unsigned int*)Abf, row_ptr, col,
                                                      dinv, b2, batch, Bm, gsum, N);
    pool_final<<<NGRAPH, 128, 0, stream>>>(gsum, gstart, gmat);
    head_kernel<<<NGRAPH, 128, 0, stream>>>(gmat, fW1, fb1, fW2, fb2, out);
}

// Round 6
// 468.918 us; speedup vs baseline: 1.6312x; 1.6312x over previous
//
#include <hip/hip_runtime.h>
#include <hip/hip_bf16.h>

#define H 128
#define DOUT 32
#define NGRAPH 64
#define MM_ROWS 64
#define PCHUNK 128
#define SORT_TILE 4096
#define NBUCK_MAX 128

// bf16 helpers (RTN-even pack, bit-shift unpack)
static __device__ __forceinline__ unsigned short f2bf(float v) {
    unsigned int u = __float_as_uint(v);
    unsigned int r = (u + 0x7FFFu + ((u >> 16) & 1u)) >> 16;
    return (unsigned short)r;
}
#define BFLO(w) __uint_as_float((w) << 16)
#define BFHI(w) __uint_as_float((w) & 0xFFFF0000u)

// ---------------- edge bucket sort (by dst >> bshift) ----------------

__global__ __launch_bounds__(256) void bucket_hist_kernel(const int* __restrict__ dst, int E,
                                                          int bshift, int* __restrict__ bcnt) {
    __shared__ int lh[NBUCK_MAX];
    int t = threadIdx.x;
    if (t < NBUCK_MAX) lh[t] = 0;
    __syncthreads();
    int base = blockIdx.x * SORT_TILE;
    int cnt = E - base;
    if (cnt > SORT_TILE) cnt = SORT_TILE;
    for (int j = t; j < cnt; j += 256) atomicAdd(&lh[dst[base + j] >> bshift], 1);
    __syncthreads();
    if (t < NBUCK_MAX && lh[t]) atomicAdd(&bcnt[t], lh[t]);
}

__global__ void bucket_scan_kernel(const int* __restrict__ bcnt, int* __restrict__ bfill,
                                   int nbuck) {
    if (threadIdx.x == 0) {
        int run = 0;
        for (int b = 0; b < nbuck; ++b) {
            bfill[b] = run;
            run += bcnt[b];
        }
    }
}

__global__ __launch_bounds__(256) void bucket_scatter_kernel(const int* __restrict__ src,
                                                             const int* __restrict__ dst, int E,
                                                             int bshift, int* __restrict__ bfill,
                                                             int2* __restrict__ es) {
    __shared__ int lh[NBUCK_MAX], lsc[NBUCK_MAX], lbase[NBUCK_MAX], lfill[NBUCK_MAX],
        ldelta[NBUCK_MAX];
    __shared__ int2 sp[SORT_TILE];
    __shared__ unsigned char sb[SORT_TILE];
    int t = threadIdx.x;
    if (t < NBUCK_MAX) {
        lh[t] = 0;
        lfill[t] = 0;
    }
    __syncthreads();
    int base = blockIdx.x * SORT_TILE;
    int cnt = E - base;
    if (cnt > SORT_TILE) cnt = SORT_TILE;
    for (int j = t; j < cnt; j += 256) atomicAdd(&lh[dst[base + j] >> bshift], 1);
    __syncthreads();
    if (t < NBUCK_MAX) lsc[t] = lh[t];
    __syncthreads();
    for (int off = 1; off < NBUCK_MAX; off <<= 1) {
        int x = 0;
        if (t < NBUCK_MAX && t >= off) x = lsc[t - off];
        __syncthreads();
        if (t < NBUCK_MAX) lsc[t] += x;
        __syncthreads();
    }
    if (t < NBUCK_MAX) {
        lbase[t] = lsc[t] - lh[t];
        if (lh[t] > 0) ldelta[t] = atomicAdd(&bfill[t], lh[t]) - lbase[t];
    }
    __syncthreads();
    for (int j = t; j < cnt; j += 256) {
        int s = src[base + j], d = dst[base + j];
        int b = d >> bshift;
        int r = atomicAdd(&lfill[b], 1);
        int slot = lbase[b] + r;
        sp[slot] = make_int2(s, d);
        sb[slot] = (unsigned char)b;
    }
    __syncthreads();
    for (int j = t; j < cnt; j += 256) {
        int b = sb[j];
        es[ldelta[b] + j] = sp[j];
    }
}

__global__ __launch_bounds__(256) void deg_hist_sorted(const int2* __restrict__ es, int E,
                                                       int* __restrict__ deg) {
    int e = blockIdx.x * 256 + threadIdx.x;
    if (e < E) atomicAdd(&deg[es[e].y], 1);
}

__global__ __launch_bounds__(256) void fill_csr_sorted(const int2* __restrict__ es, int E,
                                                       int* __restrict__ fill,
                                                       int* __restrict__ col) {
    int e = blockIdx.x * 256 + threadIdx.x;
    if (e < E) {
        int2 p = es[e];
        int pos = atomicAdd(&fill[p.y], 1);
        col[pos] = p.x;
    }
}

// ---------------- CSR row_ptr scan / misc ----------------

__global__ __launch_bounds__(256) void batch_bounds_kernel(const int* __restrict__ batch,
                                                           int N, int* __restrict__ gstart) {
    int i = blockIdx.x * 256 + threadIdx.x;
    if (i < N) {
        int b = batch[i];
        int bp = (i == 0) ? -1 : batch[i - 1];
        for (int g = bp + 1; g <= b; ++g) gstart[g] = i;
        if (i == N - 1)
            for (int g = b + 1; g <= NGRAPH; ++g) gstart[g] = N;
    }
}

__global__ __launch_bounds__(256) void scan_phase1(const int* __restrict__ deg, int N,
                                                   int* __restrict__ bsum) {
    __shared__ int sd[256];
    int t = threadIdx.x;
    int base = blockIdx.x * 1024 + t * 4;
    int s = 0;
#pragma unroll
    for (int j = 0; j < 4; ++j)
        if (base + j < N) s += deg[base + j];
    sd[t] = s;
    __syncthreads();
    for (int off = 128; off > 0; off >>= 1) {
        if (t < off) sd[t] += sd[t + off];
        __syncthreads();
    }
    if (t == 0) bsum[blockIdx.x] = sd[0];
}

__global__ void scan_phase2(int* bsum, int nb, int* __restrict__ row_ptr, int N, int E) {
    if (threadIdx.x == 0) {
        int run = 0;
        for (int i = 0; i < nb; ++i) {
            int v = bsum[i];
            bsum[i] = run;
            run += v;
        }
        row_ptr[N] = E;
    }
}

__global__ __launch_bounds__(256) void scan_phase3(const int* __restrict__ deg,
                                                   const int* __restrict__ boff, int N,
                                                   int* __restrict__ row_ptr) {
    __shared__ int sd[256];
    int t = threadIdx.x;
    int base = blockIdx.x * 1024 + t * 4;
    int v[4];
    int s = 0;
#pragma unroll
    for (int j = 0; j < 4; ++j) {
        v[j] = (base + j < N) ? deg[base + j] : 0;
        s += v[j];
    }
    sd[t] = s;
    __syncthreads();
    for (int off = 1; off < 256; off <<= 1) {
        int x = (t >= off) ? sd[t - off] : 0;
        __syncthreads();
        sd[t] += x;
        __syncthreads();
    }
    int run = boff[blockIdx.x] + sd[t] - s;
#pragma unroll
    for (int j = 0; j < 4; ++j)
        if (base + j < N) {
            row_ptr[base + j] = run;
            run += v[j];
        }
}

__global__ __launch_bounds__(256) void init_node_kernel(const int* __restrict__ deg,
                                                        const int* __restrict__ row_ptr,
                                                        float* __restrict__ dinv,
                                                        int* __restrict__ fill, int N) {
    int i = blockIdx.x * 256 + threadIdx.x;
    if (i < N) {
        dinv[i] = rsqrtf(1.0f + (float)deg[i]);
        fill[i] = row_ptr[i];
    }
}

// ---------------- compute ----------------

// Out_bf[row] = bf16((X[row] @ W) * dinv[row]);  X:[M,128] fp32, W:[128,128]
__global__ __launch_bounds__(256) void mm_scale_kernel(const float* __restrict__ X,
                                                       const float* __restrict__ W,
                                                       const float* __restrict__ dinv,
                                                       unsigned short* __restrict__ Out, int M) {
    __shared__ float xs[128 * 65];
    int tid = threadIdx.x;
    int row0 = blockIdx.x * MM_ROWS;
    int c = tid & 31, rl = tid >> 5;
#pragma unroll
    for (int p = 0; p < MM_ROWS; p += 8) {
        int m = p + rl;
        int row = row0 + m;
        float4 v = make_float4(0.f, 0.f, 0.f, 0.f);
        if (row < M) v = *reinterpret_cast<const float4*>(X + (size_t)row * H + c * 4);
        xs[(4 * c + 0) * 65 + m] = v.x;
        xs[(4 * c + 1) * 65 + m] = v.y;
        xs[(4 * c + 2) * 65 + m] = v.z;
        xs[(4 * c + 3) * 65 + m] = v.w;
    }
    __syncthreads();
    int tx = tid & 31;
    int ty = tid >> 5;
    float acc[8][4];
#pragma unroll
    for (int i = 0; i < 8; ++i)
#pragma unroll
        for (int j = 0; j < 4; ++j) acc[i][j] = 0.f;
#pragma unroll 4
    for (int k = 0; k < 128; ++k) {
        float4 w = *reinterpret_cast<const float4*>(W + k * H + tx * 4);
        float xv[8];
#pragma unroll
        for (int i = 0; i < 8; ++i) xv[i] = xs[k * 65 + ty * 8 + i];
#pragma unroll
        for (int i = 0; i < 8; ++i) {
            acc[i][0] = fmaf(xv[i], w.x, acc[i][0]);
            acc[i][1] = fmaf(xv[i], w.y, acc[i][1]);
            acc[i][2] = fmaf(xv[i], w.z, acc[i][2]);
            acc[i][3] = fmaf(xv[i], w.w, acc[i][3]);
        }
    }
#pragma unroll
    for (int i = 0; i < 8; ++i) {
        int row = row0 + ty * 8 + i;
        if (row < M) {
            float sc = dinv[row];
            unsigned int u0 = (unsigned int)f2bf(acc[i][0] * sc) |
                              ((unsigned int)f2bf(acc[i][1] * sc) << 16);
            unsigned int u1 = (unsigned int)f2bf(acc[i][2] * sc) |
                              ((unsigned int)f2bf(acc[i][3] * sc) << 16);
            *reinterpret_cast<uint2*>(Out + (size_t)row * H + tx * 4) = make_uint2(u0, u1);
        }
    }
}

// One wave per dst row; lane owns features {2*lane, 2*lane+1} (one u32 = 2 bf16).
// Out[i] = relu(dinv*(sum+self)+bias)  (fp32, coalesced 512B/wave)
__global__ __launch_bounds__(256) void agg_bf16_kernel(
    const unsigned int* __restrict__ Au, const int* __restrict__ row_ptr,
    const int* __restrict__ col, const float* __restrict__ dinv,
    const float* __restrict__ bias, float* __restrict__ Out, int N) {
    int wave = threadIdx.x >> 6;
    int lane = threadIdx.x & 63;
    int i = blockIdx.x * 4 + wave;
    if (i >= N) return;
    int s = row_ptr[i], e = row_ptr[i + 1];
    unsigned int ws = Au[(size_t)i * 64 + lane];  // self-loop term
    float acc0 = BFLO(ws), acc1 = BFHI(ws);
    int j = s;
    for (; j + 4 <= e; j += 4) {
        int c0 = col[j], c1 = col[j + 1], c2 = col[j + 2], c3 = col[j + 3];
        unsigned int w0 = Au[(size_t)c0 * 64 + lane];
        unsigned int w1 = Au[(size_t)c1 * 64 + lane];
        unsigned int w2 = Au[(size_t)c2 * 64 + lane];
        unsigned int w3 = Au[(size_t)c3 * 64 + lane];
        acc0 += BFLO(w0) + BFLO(w1);
        acc1 += BFHI(w0) + BFHI(w1);
        acc0 += BFLO(w2) + BFLO(w3);
        acc1 += BFHI(w2) + BFHI(w3);
    }
    for (; j < e; ++j) {
        unsigned int w = Au[(size_t)col[j] * 64 + lane];
        acc0 += BFLO(w);
        acc1 += BFHI(w);
    }
    float d = dinv[i];
    float o0 = fmaxf(fmaf(d, acc0, bias[2 * lane]), 0.f);
    float o1 = fmaxf(fmaf(d, acc1, bias[2 * lane + 1]), 0.f);
    *reinterpret_cast<float2*>(Out + (size_t)i * H + 2 * lane) = make_float2(o0, o1);
}

// ---------------- pooling (2-phase: register pre-reduction, few atomics) --------

__global__ __launch_bounds__(128) void pool_partial(const float* __restrict__ Bm,
                                                    const int* __restrict__ batch,
                                                    float* __restrict__ gsum, int N) {
    __shared__ int sb[PCHUNK];
    int base = blockIdx.x * PCHUNK;
    int n_here = N - base;
    if (n_here > PCHUNK) n_here = PCHUNK;
    int f = threadIdx.x;
    if (f < n_here) sb[f] = batch[base + f];
    __syncthreads();
    float acc = 0.f;
    int cur = sb[0];
    for (int j = 0; j < n_here; ++j) {
        int g = sb[j];  // wave-uniform
        if (g != cur) {
            atomicAdd(&gsum[cur * H + f], acc);
            acc = 0.f;
            cur = g;
        }
        acc += Bm[(size_t)(base + j) * H + f];
    }
    atomicAdd(&gsum[cur * H + f], acc);
}

__global__ __launch_bounds__(128) void pool_final(const float* __restrict__ gsum,
                                                  const int* __restrict__ gstart,
                                                  float* __restrict__ g) {
    int gr = blockIdx.x, f = threadIdx.x;
    int cnt = gstart[gr + 1] - gstart[gr];
    g[gr * H + f] = gsum[gr * H + f] / fmaxf((float)cnt, 1.f);
}

__global__ __launch_bounds__(128) void head_kernel(const float* __restrict__ g,
                                                   const float* __restrict__ fW1,
                                                   const float* __restrict__ fb1,
                                                   const float* __restrict__ fW2,
                                                   const float* __restrict__ fb2,
                                                   float* __restrict__ out) {
    __shared__ float gv[H], hid[H], lg[DOUT];
    int gr = blockIdx.x, f = threadIdx.x;
    gv[f] = g[gr * H + f];
    __syncthreads();
    float acc = fb1[f];
    for (int k = 0; k < H; ++k) acc = fmaf(gv[k], fW1[k * H + f], acc);
    hid[f] = fmaxf(acc, 0.f);
    __syncthreads();
    if (f < DOUT) {
        float a = fb2[f];
        for (int k = 0; k < H; ++k) a = fmaf(hid[k], fW2[k * DOUT + f], a);
        lg[f] = a;
    }
    __syncthreads();
    if (f < DOUT) {
        float mx = -1e30f;
        for (int j = 0; j < DOUT; ++j) mx = fmaxf(mx, lg[j]);
        float ssum = 0.f;
        for (int j = 0; j < DOUT; ++j) ssum += expf(lg[j] - mx);
        out[gr * DOUT + f] = expf(lg[f] - mx) / ssum;
    }
}

// ---------------- launch ----------------

extern "C" void kernel_launch(void* const* d_in, const int* in_sizes, int n_in,
                              void* d_out, int out_size, void* d_ws, size_t ws_size,
                              hipStream_t stream) {
    const float* x = (const float*)d_in[0];
    const int* edge = (const int*)d_in[1];
    const int* batch = (const int*)d_in[2];
    const float* W1 = (const float*)d_in[3];
    const float* b1 = (const float*)d_in[4];
    const float* W2 = (const float*)d_in[5];
    const float* b2 = (const float*)d_in[6];
    const float* fW1 = (const float*)d_in[7];
    const float* fb1 = (const float*)d_in[8];
    const float* fW2 = (const float*)d_in[9];
    const float* fb2 = (const float*)d_in[10];
    float* out = (float*)d_out;

    int N = in_sizes[0] / H;
    int E = in_sizes[1] / 2;
    const int* srcI = edge;
    const int* dstI = edge + E;

    char* ws = (char*)d_ws;
    size_t off = 0;
    auto alloc = [&](size_t bytes) {
        void* p = ws + off;
        off = (off + bytes + 255) & ~(size_t)255;
        return p;
    };
    int* deg = (int*)alloc((size_t)N * 4);
    int* row_ptr = (int*)alloc((size_t)(N + 1) * 4);
    int* fill = (int*)alloc((size_t)N * 4);
    int* col = (int*)alloc((size_t)E * 4);
    float* dinv = (float*)alloc((size_t)N * 4);
    int* bsum = (int*)alloc(4096);
    int* gstart = (int*)alloc(512);
    int* bcnt = (int*)alloc(NBUCK_MAX * 4);
    int* bfill = (int*)alloc(NBUCK_MAX * 4);
    float* gsum = (float*)alloc((size_t)NGRAPH * H * 4);
    float* gmat = (float*)alloc((size_t)NGRAPH * H * 4);
    // A region: holds es (E*8B) during CSR build, then bf16 activations (N*H*2B)
    unsigned short* Abf = (unsigned short*)alloc((size_t)N * H * 4);
    float* Bm = (float*)alloc((size_t)N * H * 4);
    (void)ws_size;

    int2* es = (int2*)Abf;  // consumed before mm_scale overwrites; same stream

    int bshift = 0;
    while (((N - 1) >> bshift) >= NBUCK_MAX) ++bshift;
    int nbuck = ((N - 1) >> bshift) + 1;

    hipMemsetAsync(deg, 0, (size_t)N * 4, stream);
    hipMemsetAsync(bcnt, 0, NBUCK_MAX * 4, stream);
    hipMemsetAsync(gsum, 0, (size_t)NGRAPH * H * 4, stream);

    int nb = (N + 1023) / 1024;
    int nst = (E + SORT_TILE - 1) / SORT_TILE;

    bucket_hist_kernel<<<nst, 256, 0, stream>>>(dstI, E, bshift, bcnt);
    bucket_scan_kernel<<<1, 1, 0, stream>>>(bcnt, bfill, nbuck);
    bucket_scatter_kernel<<<nst, 256, 0, stream>>>(srcI, dstI, E, bshift, bfill, es);
    deg_hist_sorted<<<(E + 255) / 256, 256, 0, stream>>>(es, E, deg);

    batch_bounds_kernel<<<(N + 255) / 256, 256, 0, stream>>>(batch, N, gstart);
    scan_phase1<<<nb, 256, 0, stream>>>(deg, N, bsum);
    scan_phase2<<<1, 1, 0, stream>>>(bsum, nb, row_ptr, N, E);
    scan_phase3<<<nb, 256, 0, stream>>>(deg, bsum, N, row_ptr);
    init_node_kernel<<<(N + 255) / 256, 256, 0, stream>>>(deg, row_ptr, dinv, fill, N);
    fill_csr_sorted<<<(E + 255) / 256, 256, 0, stream>>>(es, E, fill, col);

    int mmblocks = (N + MM_ROWS - 1) / MM_ROWS;
    int aggblocks = (N + 3) / 4;
    mm_scale_kernel<<<mmblocks, 256, 0, stream>>>(x, W1, dinv, Abf, N);
    agg_bf16_kernel<<<aggblocks, 256, 0, stream>>>((const unsigned int*)Abf, row_ptr, col,
                                                   dinv, b1, Bm, N);
    mm_scale_kernel<<<mmblocks, 256, 0, stream>>>(Bm, W2, dinv, Abf, N);
    agg_bf16_kernel<<<aggblocks, 256, 0, stream>>>((const unsigned int*)Abf, row_ptr, col,
                                                   dinv, b2, Bm, N);
    pool_partial<<<(N + PCHUNK - 1) / PCHUNK, 128, 0, stream>>>(Bm, batch, gsum, N);
    pool_final<<<NGRAPH, 128, 0, stream>>>(gsum, gstart, gmat);
    head_kernel<<<NGRAPH, 128, 0, stream>>>(gmat, fW1, fb1, fW2, fb2, out);
}

// Round 7
// 442.199 us; speedup vs baseline: 1.7297x; 1.0604x over previous
//
#include <hip/hip_runtime.h>
#include <hip/hip_bf16.h>

#define H 128
#define DOUT 32
#define NGRAPH 64
#define PCHUNK 128
#define SORT_TILE 4096
#define NBUCK_MAX 128

typedef __attribute__((ext_vector_type(8))) short bf16x8;
typedef __attribute__((ext_vector_type(4))) float f32x4;
union U4B {
    uint4 u;
    bf16x8 b;
};

// bf16 helpers (RTN-even pack, bit-shift unpack)
static __device__ __forceinline__ unsigned short f2bf(float v) {
    unsigned int u = __float_as_uint(v);
    unsigned int r = (u + 0x7FFFu + ((u >> 16) & 1u)) >> 16;
    return (unsigned short)r;
}
#define BFLO(w) __uint_as_float((w) << 16)
#define BFHI(w) __uint_as_float((w) & 0xFFFF0000u)

// ---------------- edge bucket sort (by dst >> bshift) ----------------

__global__ __launch_bounds__(256) void bucket_hist_kernel(const int* __restrict__ dst, int E,
                                                          int bshift, int* __restrict__ bcnt) {
    __shared__ int lh[NBUCK_MAX];
    int t = threadIdx.x;
    if (t < NBUCK_MAX) lh[t] = 0;
    __syncthreads();
    int base = blockIdx.x * SORT_TILE;
    int cnt = E - base;
    if (cnt > SORT_TILE) cnt = SORT_TILE;
    for (int j = t; j < cnt; j += 256) atomicAdd(&lh[dst[base + j] >> bshift], 1);
    __syncthreads();
    if (t < NBUCK_MAX && lh[t]) atomicAdd(&bcnt[t], lh[t]);
}

__global__ void bucket_scan_kernel(const int* __restrict__ bcnt, int* __restrict__ bfill,
                                   int nbuck) {
    if (threadIdx.x == 0) {
        int run = 0;
        for (int b = 0; b < nbuck; ++b) {
            bfill[b] = run;
            run += bcnt[b];
        }
    }
}

__global__ __launch_bounds__(256) void bucket_scatter_kernel(const int* __restrict__ src,
                                                             const int* __restrict__ dst, int E,
                                                             int bshift, int* __restrict__ bfill,
                                                             int2* __restrict__ es) {
    __shared__ int lh[NBUCK_MAX], lsc[NBUCK_MAX], lbase[NBUCK_MAX], lfill[NBUCK_MAX],
        ldelta[NBUCK_MAX];
    __shared__ int2 sp[SORT_TILE];
    __shared__ unsigned char sb[SORT_TILE];
    int t = threadIdx.x;
    if (t < NBUCK_MAX) {
        lh[t] = 0;
        lfill[t] = 0;
    }
    __syncthreads();
    int base = blockIdx.x * SORT_TILE;
    int cnt = E - base;
    if (cnt > SORT_TILE) cnt = SORT_TILE;
    for (int j = t; j < cnt; j += 256) atomicAdd(&lh[dst[base + j] >> bshift], 1);
    __syncthreads();
    if (t < NBUCK_MAX) lsc[t] = lh[t];
    __syncthreads();
    for (int off = 1; off < NBUCK_MAX; off <<= 1) {
        int x = 0;
        if (t < NBUCK_MAX && t >= off) x = lsc[t - off];
        __syncthreads();
        if (t < NBUCK_MAX) lsc[t] += x;
        __syncthreads();
    }
    if (t < NBUCK_MAX) {
        lbase[t] = lsc[t] - lh[t];
        if (lh[t] > 0) ldelta[t] = atomicAdd(&bfill[t], lh[t]) - lbase[t];
    }
    __syncthreads();
    for (int j = t; j < cnt; j += 256) {
        int s = src[base + j], d = dst[base + j];
        int b = d >> bshift;
        int r = atomicAdd(&lfill[b], 1);
        int slot = lbase[b] + r;
        sp[slot] = make_int2(s, d);
        sb[slot] = (unsigned char)b;
    }
    __syncthreads();
    for (int j = t; j < cnt; j += 256) {
        int b = sb[j];
        es[ldelta[b] + j] = sp[j];
    }
}

__global__ __launch_bounds__(256) void deg_hist_sorted(const int2* __restrict__ es, int E,
                                                       int* __restrict__ deg) {
    int e = blockIdx.x * 256 + threadIdx.x;
    if (e < E) atomicAdd(&deg[es[e].y], 1);
}

__global__ __launch_bounds__(256) void fill_csr_sorted(const int2* __restrict__ es, int E,
                                                       int* __restrict__ fill,
                                                       int* __restrict__ col) {
    int e = blockIdx.x * 256 + threadIdx.x;
    if (e < E) {
        int2 p = es[e];
        int pos = atomicAdd(&fill[p.y], 1);
        col[pos] = p.x;
    }
}

// ---------------- CSR row_ptr scan / misc ----------------

__global__ __launch_bounds__(256) void batch_bounds_kernel(const int* __restrict__ batch,
                                                           int N, int* __restrict__ gstart) {
    int i = blockIdx.x * 256 + threadIdx.x;
    if (i < N) {
        int b = batch[i];
        int bp = (i == 0) ? -1 : batch[i - 1];
        for (int g = bp + 1; g <= b; ++g) gstart[g] = i;
        if (i == N - 1)
            for (int g = b + 1; g <= NGRAPH; ++g) gstart[g] = N;
    }
}

__global__ __launch_bounds__(256) void scan_phase1(const int* __restrict__ deg, int N,
                                                   int* __restrict__ bsum) {
    __shared__ int sd[256];
    int t = threadIdx.x;
    int base = blockIdx.x * 1024 + t * 4;
    int s = 0;
#pragma unroll
    for (int j = 0; j < 4; ++j)
        if (base + j < N) s += deg[base + j];
    sd[t] = s;
    __syncthreads();
    for (int off = 128; off > 0; off >>= 1) {
        if (t < off) sd[t] += sd[t + off];
        __syncthreads();
    }
    if (t == 0) bsum[blockIdx.x] = sd[0];
}

__global__ void scan_phase2(int* bsum, int nb, int* __restrict__ row_ptr, int N, int E) {
    if (threadIdx.x == 0) {
        int run = 0;
        for (int i = 0; i < nb; ++i) {
            int v = bsum[i];
            bsum[i] = run;
            run += v;
        }
        row_ptr[N] = E;
    }
}

__global__ __launch_bounds__(256) void scan_phase3(const int* __restrict__ deg,
                                                   const int* __restrict__ boff, int N,
                                                   int* __restrict__ row_ptr) {
    __shared__ int sd[256];
    int t = threadIdx.x;
    int base = blockIdx.x * 1024 + t * 4;
    int v[4];
    int s = 0;
#pragma unroll
    for (int j = 0; j < 4; ++j) {
        v[j] = (base + j < N) ? deg[base + j] : 0;
        s += v[j];
    }
    sd[t] = s;
    __syncthreads();
    for (int off = 1; off < 256; off <<= 1) {
        int x = (t >= off) ? sd[t - off] : 0;
        __syncthreads();
        sd[t] += x;
        __syncthreads();
    }
    int run = boff[blockIdx.x] + sd[t] - s;
#pragma unroll
    for (int j = 0; j < 4; ++j)
        if (base + j < N) {
            row_ptr[base + j] = run;
            run += v[j];
        }
}

__global__ __launch_bounds__(256) void init_node_kernel(const int* __restrict__ deg,
                                                        const int* __restrict__ row_ptr,
                                                        float* __restrict__ dinv,
                                                        int* __restrict__ fill, int N) {
    int i = blockIdx.x * 256 + threadIdx.x;
    if (i < N) {
        dinv[i] = rsqrtf(1.0f + (float)deg[i]);
        fill[i] = row_ptr[i];
    }
}

// ---------------- MFMA matmul ----------------
// Out_bf[row] = bf16((X[row] @ W) * dinv[row]); block = 128 rows x 128 cols,
// 4 waves, mfma_f32_16x16x32_bf16. W staged in LDS bf16, chunk-XOR swizzled.
template <int IN_BF16>
__global__ __launch_bounds__(256) void mm_mfma_kernel(const void* __restrict__ Xv,
                                                      const float* __restrict__ W,
                                                      const float* __restrict__ dinv,
                                                      unsigned short* __restrict__ Out, int M) {
    __shared__ unsigned int wlds[128 * 64];  // [col][64 u32]; chunk p = c ^ (col&15)
    int t = threadIdx.x;
#pragma unroll
    for (int it = 0; it < 8; ++it) {
        int q = t + it * 256;  // chunk id 0..2047
        int colq = q >> 4, cq = q & 15;
        unsigned int wrd[4];
#pragma unroll
        for (int wI = 0; wI < 4; ++wI) {
            float f0 = W[(8 * cq + 2 * wI) * H + colq];
            float f1 = W[(8 * cq + 2 * wI + 1) * H + colq];
            wrd[wI] = (unsigned int)f2bf(f0) | ((unsigned int)f2bf(f1) << 16);
        }
        int p = cq ^ (colq & 15);
        *reinterpret_cast<uint4*>(&wlds[colq * 64 + p * 4]) =
            make_uint4(wrd[0], wrd[1], wrd[2], wrd[3]);
    }
    __syncthreads();

    int wv = t >> 6, l = t & 63;
    int l16 = l & 15, lk = l >> 4;
    int rowbase = blockIdx.x * 128 + wv * 32;

    f32x4 acc[2][8];
#pragma unroll
    for (int rt = 0; rt < 2; ++rt)
#pragma unroll
        for (int nt = 0; nt < 8; ++nt) acc[rt][nt] = (f32x4){0.f, 0.f, 0.f, 0.f};

#pragma unroll
    for (int ks = 0; ks < 4; ++ks) {
        U4B afr[2];
#pragma unroll
        for (int rt = 0; rt < 2; ++rt) {
            int row = rowbase + rt * 16 + l16;
            if (IN_BF16) {
                uint4 v = make_uint4(0u, 0u, 0u, 0u);
                if (row < M) v = *((const uint4*)Xv + (size_t)row * 16 + 4 * ks + lk);
                afr[rt].u = v;
            } else {
                const float* X = (const float*)Xv;
                float4 v0 = make_float4(0.f, 0.f, 0.f, 0.f), v1 = v0;
                if (row < M) {
                    v0 = *reinterpret_cast<const float4*>(X + (size_t)row * H + 32 * ks +
                                                          8 * lk);
                    v1 = *reinterpret_cast<const float4*>(X + (size_t)row * H + 32 * ks +
                                                          8 * lk + 4);
                }
                afr[rt].u.x = (unsigned int)f2bf(v0.x) | ((unsigned int)f2bf(v0.y) << 16);
                afr[rt].u.y = (unsigned int)f2bf(v0.z) | ((unsigned int)f2bf(v0.w) << 16);
                afr[rt].u.z = (unsigned int)f2bf(v1.x) | ((unsigned int)f2bf(v1.y) << 16);
                afr[rt].u.w = (unsigned int)f2bf(v1.z) | ((unsigned int)f2bf(v1.w) << 16);
            }
        }
#pragma unroll
        for (int nt = 0; nt < 8; ++nt) {
            int colB = nt * 16 + l16;
            int c = 4 * ks + lk;
            int p = c ^ (colB & 15);
            U4B bfr;
            bfr.u = *reinterpret_cast<const uint4*>(&wlds[colB * 64 + p * 4]);
            acc[0][nt] = __builtin_amdgcn_mfma_f32_16x16x32_bf16(afr[0].b, bfr.b, acc[0][nt],
                                                                 0, 0, 0);
            acc[1][nt] = __builtin_amdgcn_mfma_f32_16x16x32_bf16(afr[1].b, bfr.b, acc[1][nt],
                                                                 0, 0, 0);
        }
    }

#pragma unroll
    for (int rt = 0; rt < 2; ++rt) {
#pragma unroll
        for (int r = 0; r < 4; ++r) {
            int row = rowbase + rt * 16 + lk * 4 + r;
            if (row < M) {
                float dsc = dinv[row];
#pragma unroll
                for (int nt = 0; nt < 8; ++nt)
                    Out[(size_t)row * H + nt * 16 + l16] = f2bf(acc[rt][nt][r] * dsc);
            }
        }
    }
}

// One wave per dst row; lane owns features {2*lane, 2*lane+1} (one u32 = 2 bf16).
__global__ __launch_bounds__(256) void agg_bf16_kernel(
    const unsigned int* __restrict__ Au, const int* __restrict__ row_ptr,
    const int* __restrict__ col, const float* __restrict__ dinv,
    const float* __restrict__ bias, unsigned int* __restrict__ OutBf, int N) {
    int wave = threadIdx.x >> 6;
    int lane = threadIdx.x & 63;
    int i = blockIdx.x * 4 + wave;
    if (i >= N) return;
    int s = row_ptr[i], e = row_ptr[i + 1];
    unsigned int ws = Au[(size_t)i * 64 + lane];  // self-loop term
    float acc0 = BFLO(ws), acc1 = BFHI(ws);
    int j = s;
    for (; j + 4 <= e; j += 4) {
        int c0 = col[j], c1 = col[j + 1], c2 = col[j + 2], c3 = col[j + 3];
        unsigned int w0 = Au[(size_t)c0 * 64 + lane];
        unsigned int w1 = Au[(size_t)c1 * 64 + lane];
        unsigned int w2 = Au[(size_t)c2 * 64 + lane];
        unsigned int w3 = Au[(size_t)c3 * 64 + lane];
        acc0 += BFLO(w0) + BFLO(w1);
        acc1 += BFHI(w0) + BFHI(w1);
        acc0 += BFLO(w2) + BFLO(w3);
        acc1 += BFHI(w2) + BFHI(w3);
    }
    for (; j < e; ++j) {
        unsigned int w = Au[(size_t)col[j] * 64 + lane];
        acc0 += BFLO(w);
        acc1 += BFHI(w);
    }
    float d = dinv[i];
    float o0 = fmaxf(fmaf(d, acc0, bias[2 * lane]), 0.f);
    float o1 = fmaxf(fmaf(d, acc1, bias[2 * lane + 1]), 0.f);
    OutBf[(size_t)i * 64 + lane] = (unsigned int)f2bf(o0) | ((unsigned int)f2bf(o1) << 16);
}

// ---------------- pooling (bf16 input, register pre-reduction) ----------------

__global__ __launch_bounds__(64) void pool_partial(const unsigned int* __restrict__ Bu,
                                                   const int* __restrict__ batch,
                                                   float* __restrict__ gsum, int N) {
    __shared__ int sb[PCHUNK];
    int base = blockIdx.x * PCHUNK;
    int n_here = N - base;
    if (n_here > PCHUNK) n_here = PCHUNK;
    int f = threadIdx.x;  // u32 feature-pair index 0..63
    for (int j = f; j < n_here; j += 64) sb[j] = batch[base + j];
    __syncthreads();
    float acc0 = 0.f, acc1 = 0.f;
    int cur = sb[0];
    for (int j = 0; j < n_here; ++j) {
        int g = sb[j];  // wave-uniform
        if (g != cur) {
            atomicAdd(&gsum[cur * H + 2 * f], acc0);
            atomicAdd(&gsum[cur * H + 2 * f + 1], acc1);
            acc0 = 0.f;
            acc1 = 0.f;
            cur = g;
        }
        unsigned int w = Bu[(size_t)(base + j) * 64 + f];
        acc0 += BFLO(w);
        acc1 += BFHI(w);
    }
    atomicAdd(&gsum[cur * H + 2 * f], acc0);
    atomicAdd(&gsum[cur * H + 2 * f + 1], acc1);
}

__global__ __launch_bounds__(128) void pool_final(const float* __restrict__ gsum,
                                                  const int* __restrict__ gstart,
                                                  float* __restrict__ g) {
    int gr = blockIdx.x, f = threadIdx.x;
    int cnt = gstart[gr + 1] - gstart[gr];
    g[gr * H + f] = gsum[gr * H + f] / fmaxf((float)cnt, 1.f);
}

__global__ __launch_bounds__(128) void head_kernel(const float* __restrict__ g,
                                                   const float* __restrict__ fW1,
                                                   const float* __restrict__ fb1,
                                                   const float* __restrict__ fW2,
                                                   const float* __restrict__ fb2,
                                                   float* __restrict__ out) {
    __shared__ float gv[H], hid[H], lg[DOUT];
    int gr = blockIdx.x, f = threadIdx.x;
    gv[f] = g[gr * H + f];
    __syncthreads();
    float acc = fb1[f];
    for (int k = 0; k < H; ++k) acc = fmaf(gv[k], fW1[k * H + f], acc);
    hid[f] = fmaxf(acc, 0.f);
    __syncthreads();
    if (f < DOUT) {
        float a = fb2[f];
        for (int k = 0; k < H; ++k) a = fmaf(hid[k], fW2[k * DOUT + f], a);
        lg[f] = a;
    }
    __syncthreads();
    if (f < DOUT) {
        float mx = -1e30f;
        for (int j = 0; j < DOUT; ++j) mx = fmaxf(mx, lg[j]);
        float ssum = 0.f;
        for (int j = 0; j < DOUT; ++j) ssum += expf(lg[j] - mx);
        out[gr * DOUT + f] = expf(lg[f] - mx) / ssum;
    }
}

// ---------------- launch ----------------

extern "C" void kernel_launch(void* const* d_in, const int* in_sizes, int n_in,
                              void* d_out, int out_size, void* d_ws, size_t ws_size,
                              hipStream_t stream) {
    const float* x = (const float*)d_in[0];
    const int* edge = (const int*)d_in[1];
    const int* batch = (const int*)d_in[2];
    const float* W1 = (const float*)d_in[3];
    const float* b1 = (const float*)d_in[4];
    const float* W2 = (const float*)d_in[5];
    const float* b2 = (const float*)d_in[6];
    const float* fW1 = (const float*)d_in[7];
    const float* fb1 = (const float*)d_in[8];
    const float* fW2 = (const float*)d_in[9];
    const float* fb2 = (const float*)d_in[10];
    float* out = (float*)d_out;

    int N = in_sizes[0] / H;
    int E = in_sizes[1] / 2;
    const int* srcI = edge;
    const int* dstI = edge + E;

    char* ws = (char*)d_ws;
    size_t off = 0;
    auto alloc = [&](size_t bytes) {
        void* p = ws + off;
        off = (off + bytes + 255) & ~(size_t)255;
        return p;
    };
    int* deg = (int*)alloc((size_t)N * 4);
    int* row_ptr = (int*)alloc((size_t)(N + 1) * 4);
    int* fill = (int*)alloc((size_t)N * 4);
    int* col = (int*)alloc((size_t)E * 4);
    float* dinv = (float*)alloc((size_t)N * 4);
    int* bsum = (int*)alloc(4096);
    int* gstart = (int*)alloc(512);
    int* bcnt = (int*)alloc(NBUCK_MAX * 4);
    int* bfill = (int*)alloc(NBUCK_MAX * 4);
    float* gsum = (float*)alloc((size_t)NGRAPH * H * 4);
    float* gmat = (float*)alloc((size_t)NGRAPH * H * 4);
    // A region: holds es (E*8B) during CSR build, then bf16 activations (N*H*2B)
    unsigned short* Abf = (unsigned short*)alloc((size_t)N * H * 4);
    unsigned int* Bbf = (unsigned int*)alloc((size_t)N * H * 4);
    (void)ws_size;

    int2* es = (int2*)Abf;  // consumed before mm overwrites; same stream

    int bshift = 0;
    while (((N - 1) >> bshift) >= NBUCK_MAX) ++bshift;
    int nbuck = ((N - 1) >> bshift) + 1;

    hipMemsetAsync(deg, 0, (size_t)N * 4, stream);
    hipMemsetAsync(bcnt, 0, NBUCK_MAX * 4, stream);
    hipMemsetAsync(gsum, 0, (size_t)NGRAPH * H * 4, stream);

    int nb = (N + 1023) / 1024;
    int nst = (E + SORT_TILE - 1) / SORT_TILE;

    bucket_hist_kernel<<<nst, 256, 0, stream>>>(dstI, E, bshift, bcnt);
    bucket_scan_kernel<<<1, 1, 0, stream>>>(bcnt, bfill, nbuck);
    bucket_scatter_kernel<<<nst, 256, 0, stream>>>(srcI, dstI, E, bshift, bfill, es);
    deg_hist_sorted<<<(E + 255) / 256, 256, 0, stream>>>(es, E, deg);

    batch_bounds_kernel<<<(N + 255) / 256, 256, 0, stream>>>(batch, N, gstart);
    scan_phase1<<<nb, 256, 0, stream>>>(deg, N, bsum);
    scan_phase2<<<1, 1, 0, stream>>>(bsum, nb, row_ptr, N, E);
    scan_phase3<<<nb, 256, 0, stream>>>(deg, bsum, N, row_ptr);
    init_node_kernel<<<(N + 255) / 256, 256, 0, stream>>>(deg, row_ptr, dinv, fill, N);
    fill_csr_sorted<<<(E + 255) / 256, 256, 0, stream>>>(es, E, fill, col);

    int mmblocks = (N + 127) / 128;
    int aggblocks = (N + 3) / 4;
    mm_mfma_kernel<0><<<mmblocks, 256, 0, stream>>>(x, W1, dinv, Abf, N);
    agg_bf16_kernel<<<aggblocks, 256, 0, stream>>>((const unsigned int*)Abf, row_ptr, col,
                                                   dinv, b1, Bbf, N);
    mm_mfma_kernel<1><<<mmblocks, 256, 0, stream>>>(Bbf, W2, dinv, Abf, N);
    agg_bf16_kernel<<<aggblocks, 256, 0, stream>>>((const unsigned int*)Abf, row_ptr, col,
                                                   dinv, b2, Bbf, N);
    pool_partial<<<(N + PCHUNK - 1) / PCHUNK, 64, 0, stream>>>(Bbf, batch, gsum, N);
    pool_final<<<NGRAPH, 128, 0, stream>>>(gsum, gstart, gmat);
    head_kernel<<<NGRAPH, 128, 0, stream>>>(gmat, fW1, fb1, fW2, fb2, out);
}

// Round 8
// 383.430 us; speedup vs baseline: 1.9949x; 1.1533x over previous
//
#include <hip/hip_runtime.h>
#include <hip/hip_bf16.h>

#define H 128
#define DOUT 32
#define NGRAPH 64
#define PCHUNK 128
#define SORT_TILE 4096
#define NBUCK_MAX 128

typedef __attribute__((ext_vector_type(8))) short bf16x8;
typedef __attribute__((ext_vector_type(4))) float f32x4;
union U4B {
    uint4 u;
    bf16x8 b;
};

// bf16 helpers (RTN-even pack, bit-shift unpack)
static __device__ __forceinline__ unsigned short f2bf(float v) {
    unsigned int u = __float_as_uint(v);
    unsigned int r = (u + 0x7FFFu + ((u >> 16) & 1u)) >> 16;
    return (unsigned short)r;
}
#define BFLO(w) __uint_as_float((w) << 16)
#define BFHI(w) __uint_as_float((w) & 0xFFFF0000u)

// ---------------- edge bucket sort (by dst >> bshift) ----------------

__global__ __launch_bounds__(256) void bucket_hist_kernel(const int* __restrict__ dst, int E,
                                                          int bshift, int* __restrict__ bcnt) {
    __shared__ int lh[NBUCK_MAX];
    int t = threadIdx.x;
    if (t < NBUCK_MAX) lh[t] = 0;
    __syncthreads();
    int base = blockIdx.x * SORT_TILE;
    int cnt = E - base;
    if (cnt > SORT_TILE) cnt = SORT_TILE;
    for (int j = t; j < cnt; j += 256) atomicAdd(&lh[dst[base + j] >> bshift], 1);
    __syncthreads();
    if (t < NBUCK_MAX && lh[t]) atomicAdd(&bcnt[t], lh[t]);
}

__global__ void bucket_scan_kernel(const int* __restrict__ bcnt, int* __restrict__ bfill,
                                   int nbuck) {
    if (threadIdx.x == 0) {
        int run = 0;
        for (int b = 0; b < nbuck; ++b) {
            bfill[b] = run;
            run += bcnt[b];
        }
    }
}

// Bin a tile in LDS, reserve contiguous global range per (block,bucket),
// write out coalesced. Also accumulates deg[dst] (localized: sorted runs).
__global__ __launch_bounds__(256) void bucket_scatter_kernel(const int* __restrict__ src,
                                                             const int* __restrict__ dst, int E,
                                                             int bshift, int* __restrict__ bfill,
                                                             int2* __restrict__ es,
                                                             int* __restrict__ deg) {
    __shared__ int lh[NBUCK_MAX], lsc[NBUCK_MAX], lbase[NBUCK_MAX], lfill[NBUCK_MAX],
        ldelta[NBUCK_MAX];
    __shared__ int2 sp[SORT_TILE];
    __shared__ unsigned char sb[SORT_TILE];
    int t = threadIdx.x;
    if (t < NBUCK_MAX) {
        lh[t] = 0;
        lfill[t] = 0;
    }
    __syncthreads();
    int base = blockIdx.x * SORT_TILE;
    int cnt = E - base;
    if (cnt > SORT_TILE) cnt = SORT_TILE;
    for (int j = t; j < cnt; j += 256) atomicAdd(&lh[dst[base + j] >> bshift], 1);
    __syncthreads();
    if (t < NBUCK_MAX) lsc[t] = lh[t];
    __syncthreads();
    for (int off = 1; off < NBUCK_MAX; off <<= 1) {
        int x = 0;
        if (t < NBUCK_MAX && t >= off) x = lsc[t - off];
        __syncthreads();
        if (t < NBUCK_MAX) lsc[t] += x;
        __syncthreads();
    }
    if (t < NBUCK_MAX) {
        lbase[t] = lsc[t] - lh[t];
        if (lh[t] > 0) ldelta[t] = atomicAdd(&bfill[t], lh[t]) - lbase[t];
    }
    __syncthreads();
    for (int j = t; j < cnt; j += 256) {
        int s = src[base + j], d = dst[base + j];
        int b = d >> bshift;
        int r = atomicAdd(&lfill[b], 1);
        int slot = lbase[b] + r;
        sp[slot] = make_int2(s, d);
        sb[slot] = (unsigned char)b;
    }
    __syncthreads();
    for (int j = t; j < cnt; j += 256) {
        int b = sb[j];
        int2 p = sp[j];
        es[ldelta[b] + j] = p;
        atomicAdd(&deg[p.y], 1);  // localized: p.y within one 1024-node bucket
    }
}

__global__ __launch_bounds__(256) void fill_csr_sorted(const int2* __restrict__ es, int E,
                                                       int* __restrict__ fill,
                                                       int* __restrict__ col) {
    int e = blockIdx.x * 256 + threadIdx.x;
    if (e < E) {
        int2 p = es[e];
        int pos = atomicAdd(&fill[p.y], 1);
        col[pos] = p.x;
    }
}

// ---------------- CSR row_ptr scan / misc ----------------

__global__ __launch_bounds__(256) void batch_bounds_kernel(const int* __restrict__ batch,
                                                           int N, int* __restrict__ gstart) {
    int i = blockIdx.x * 256 + threadIdx.x;
    if (i < N) {
        int b = batch[i];
        int bp = (i == 0) ? -1 : batch[i - 1];
        for (int g = bp + 1; g <= b; ++g) gstart[g] = i;
        if (i == N - 1)
            for (int g = b + 1; g <= NGRAPH; ++g) gstart[g] = N;
    }
}

__global__ __launch_bounds__(256) void scan_phase1(const int* __restrict__ deg, int N,
                                                   int* __restrict__ bsum) {
    __shared__ int sd[256];
    int t = threadIdx.x;
    int base = blockIdx.x * 1024 + t * 4;
    int s = 0;
#pragma unroll
    for (int j = 0; j < 4; ++j)
        if (base + j < N) s += deg[base + j];
    sd[t] = s;
    __syncthreads();
    for (int off = 128; off > 0; off >>= 1) {
        if (t < off) sd[t] += sd[t + off];
        __syncthreads();
    }
    if (t == 0) bsum[blockIdx.x] = sd[0];
}

__global__ void scan_phase2(int* bsum, int nb, int* __restrict__ row_ptr, int N, int E) {
    if (threadIdx.x == 0) {
        int run = 0;
        for (int i = 0; i < nb; ++i) {
            int v = bsum[i];
            bsum[i] = run;
            run += v;
        }
        row_ptr[N] = E;
    }
}

// scan_phase3 + init_node fused: emits row_ptr, fill copy, dinv
__global__ __launch_bounds__(256) void scan_phase3(const int* __restrict__ deg,
                                                   const int* __restrict__ boff, int N,
                                                   int* __restrict__ row_ptr,
                                                   int* __restrict__ fill,
                                                   float* __restrict__ dinv) {
    __shared__ int sd[256];
    int t = threadIdx.x;
    int base = blockIdx.x * 1024 + t * 4;
    int v[4];
    int s = 0;
#pragma unroll
    for (int j = 0; j < 4; ++j) {
        v[j] = (base + j < N) ? deg[base + j] : 0;
        s += v[j];
    }
    sd[t] = s;
    __syncthreads();
    for (int off = 1; off < 256; off <<= 1) {
        int x = (t >= off) ? sd[t - off] : 0;
        __syncthreads();
        sd[t] += x;
        __syncthreads();
    }
    int run = boff[blockIdx.x] + sd[t] - s;
#pragma unroll
    for (int j = 0; j < 4; ++j)
        if (base + j < N) {
            row_ptr[base + j] = run;
            fill[base + j] = run;
            dinv[base + j] = rsqrtf(1.0f + (float)v[j]);
            run += v[j];
        }
}

// ---------------- W preprocessing: bf16-packed, swizzled-LDS layout ----------------
// Wbf[colq*64 + p*4 + wI] packs k = {8*cq+2*wI, +1} for column colq,
// where cq = p ^ (colq & 15). mm stages this with a straight coalesced copy.
__global__ __launch_bounds__(256) void prep_w_kernel(const float* __restrict__ W,
                                                     unsigned int* __restrict__ Wbf) {
    int q = blockIdx.x * 256 + threadIdx.x;  // 0..8191
    int colq = q >> 6, j = q & 63;
    int p = j >> 2, wI = j & 3;
    int cq = p ^ (colq & 15);
    int k0 = 8 * cq + 2 * wI;
    Wbf[q] = (unsigned int)f2bf(W[k0 * H + colq]) |
             ((unsigned int)f2bf(W[(k0 + 1) * H + colq]) << 16);
}

// ---------------- MFMA matmul ----------------
// Out_bf[row] = bf16((X[row] @ W) * dinv[row]); block = 128 rows, 4 waves,
// mfma_f32_16x16x32_bf16. W pre-swizzled in Wbf; staging = coalesced copy.
template <int IN_BF16>
__global__ __launch_bounds__(256) void mm_mfma_kernel(const void* __restrict__ Xv,
                                                      const unsigned int* __restrict__ Wbf,
                                                      const float* __restrict__ dinv,
                                                      unsigned short* __restrict__ Out, int M) {
    __shared__ unsigned int wlds[128 * 64];
    int t = threadIdx.x;
    const uint4* Wv = (const uint4*)Wbf;
#pragma unroll
    for (int it = 0; it < 8; ++it)
        ((uint4*)wlds)[t + it * 256] = Wv[t + it * 256];
    __syncthreads();

    int wv = t >> 6, l = t & 63;
    int l16 = l & 15, lk = l >> 4;
    int rowbase = blockIdx.x * 128 + wv * 32;

    f32x4 acc[2][8];
#pragma unroll
    for (int rt = 0; rt < 2; ++rt)
#pragma unroll
        for (int nt = 0; nt < 8; ++nt) acc[rt][nt] = (f32x4){0.f, 0.f, 0.f, 0.f};

#pragma unroll
    for (int ks = 0; ks < 4; ++ks) {
        U4B afr[2];
#pragma unroll
        for (int rt = 0; rt < 2; ++rt) {
            int row = rowbase + rt * 16 + l16;
            if (IN_BF16) {
                uint4 v = make_uint4(0u, 0u, 0u, 0u);
                if (row < M) v = *((const uint4*)Xv + (size_t)row * 16 + 4 * ks + lk);
                afr[rt].u = v;
            } else {
                const float* X = (const float*)Xv;
                float4 v0 = make_float4(0.f, 0.f, 0.f, 0.f), v1 = v0;
                if (row < M) {
                    v0 = *reinterpret_cast<const float4*>(X + (size_t)row * H + 32 * ks +
                                                          8 * lk);
                    v1 = *reinterpret_cast<const float4*>(X + (size_t)row * H + 32 * ks +
                                                          8 * lk + 4);
                }
                afr[rt].u.x = (unsigned int)f2bf(v0.x) | ((unsigned int)f2bf(v0.y) << 16);
                afr[rt].u.y = (unsigned int)f2bf(v0.z) | ((unsigned int)f2bf(v0.w) << 16);
                afr[rt].u.z = (unsigned int)f2bf(v1.x) | ((unsigned int)f2bf(v1.y) << 16);
                afr[rt].u.w = (unsigned int)f2bf(v1.z) | ((unsigned int)f2bf(v1.w) << 16);
            }
        }
#pragma unroll
        for (int nt = 0; nt < 8; ++nt) {
            int colB = nt * 16 + l16;
            int c = 4 * ks + lk;
            int p = c ^ (colB & 15);
            U4B bfr;
            bfr.u = *reinterpret_cast<const uint4*>(&wlds[colB * 64 + p * 4]);
            acc[0][nt] = __builtin_amdgcn_mfma_f32_16x16x32_bf16(afr[0].b, bfr.b, acc[0][nt],
                                                                 0, 0, 0);
            acc[1][nt] = __builtin_amdgcn_mfma_f32_16x16x32_bf16(afr[1].b, bfr.b, acc[1][nt],
                                                                 0, 0, 0);
        }
    }

#pragma unroll
    for (int rt = 0; rt < 2; ++rt) {
#pragma unroll
        for (int r = 0; r < 4; ++r) {
            int row = rowbase + rt * 16 + lk * 4 + r;
            if (row < M) {
                float dsc = dinv[row];
#pragma unroll
                for (int nt = 0; nt < 8; ++nt)
                    Out[(size_t)row * H + nt * 16 + l16] = f2bf(acc[rt][nt][r] * dsc);
            }
        }
    }
}

// One wave per dst row; lane owns one u32 = 2 bf16 features. 8-deep MLP unroll.
__global__ __launch_bounds__(256) void agg_bf16_kernel(
    const unsigned int* __restrict__ Au, const int* __restrict__ row_ptr,
    const int* __restrict__ col, const float* __restrict__ dinv,
    const float* __restrict__ bias, unsigned int* __restrict__ OutBf, int N) {
    int wave = threadIdx.x >> 6;
    int lane = threadIdx.x & 63;
    int i = blockIdx.x * 4 + wave;
    if (i >= N) return;
    int s = row_ptr[i], e = row_ptr[i + 1];
    unsigned int ws = Au[(size_t)i * 64 + lane];  // self-loop term
    float acc0 = BFLO(ws), acc1 = BFHI(ws);
    int j = s;
    for (; j + 8 <= e; j += 8) {
        int c0 = col[j], c1 = col[j + 1], c2 = col[j + 2], c3 = col[j + 3];
        int c4 = col[j + 4], c5 = col[j + 5], c6 = col[j + 6], c7 = col[j + 7];
        unsigned int w0 = Au[(size_t)c0 * 64 + lane];
        unsigned int w1 = Au[(size_t)c1 * 64 + lane];
        unsigned int w2 = Au[(size_t)c2 * 64 + lane];
        unsigned int w3 = Au[(size_t)c3 * 64 + lane];
        unsigned int w4 = Au[(size_t)c4 * 64 + lane];
        unsigned int w5 = Au[(size_t)c5 * 64 + lane];
        unsigned int w6 = Au[(size_t)c6 * 64 + lane];
        unsigned int w7 = Au[(size_t)c7 * 64 + lane];
        acc0 += BFLO(w0) + BFLO(w1);
        acc1 += BFHI(w0) + BFHI(w1);
        acc0 += BFLO(w2) + BFLO(w3);
        acc1 += BFHI(w2) + BFHI(w3);
        acc0 += BFLO(w4) + BFLO(w5);
        acc1 += BFHI(w4) + BFHI(w5);
        acc0 += BFLO(w6) + BFLO(w7);
        acc1 += BFHI(w6) + BFHI(w7);
    }
    for (; j + 4 <= e; j += 4) {
        int c0 = col[j], c1 = col[j + 1], c2 = col[j + 2], c3 = col[j + 3];
        unsigned int w0 = Au[(size_t)c0 * 64 + lane];
        unsigned int w1 = Au[(size_t)c1 * 64 + lane];
        unsigned int w2 = Au[(size_t)c2 * 64 + lane];
        unsigned int w3 = Au[(size_t)c3 * 64 + lane];
        acc0 += BFLO(w0) + BFLO(w1);
        acc1 += BFHI(w0) + BFHI(w1);
        acc0 += BFLO(w2) + BFLO(w3);
        acc1 += BFHI(w2) + BFHI(w3);
    }
    for (; j < e; ++j) {
        unsigned int w = Au[(size_t)col[j] * 64 + lane];
        acc0 += BFLO(w);
        acc1 += BFHI(w);
    }
    float d = dinv[i];
    float o0 = fmaxf(fmaf(d, acc0, bias[2 * lane]), 0.f);
    float o1 = fmaxf(fmaf(d, acc1, bias[2 * lane + 1]), 0.f);
    OutBf[(size_t)i * 64 + lane] = (unsigned int)f2bf(o0) | ((unsigned int)f2bf(o1) << 16);
}

// ---------------- pooling (bf16 input, register pre-reduction) ----------------

__global__ __launch_bounds__(64) void pool_partial(const unsigned int* __restrict__ Bu,
                                                   const int* __restrict__ batch,
                                                   float* __restrict__ gsum, int N) {
    __shared__ int sb[PCHUNK];
    int base = blockIdx.x * PCHUNK;
    int n_here = N - base;
    if (n_here > PCHUNK) n_here = PCHUNK;
    int f = threadIdx.x;  // u32 feature-pair index 0..63
    for (int j = f; j < n_here; j += 64) sb[j] = batch[base + j];
    __syncthreads();
    float acc0 = 0.f, acc1 = 0.f;
    int cur = sb[0];
    for (int j = 0; j < n_here; ++j) {
        int g = sb[j];  // wave-uniform
        if (g != cur) {
            atomicAdd(&gsum[cur * H + 2 * f], acc0);
            atomicAdd(&gsum[cur * H + 2 * f + 1], acc1);
            acc0 = 0.f;
            acc1 = 0.f;
            cur = g;
        }
        unsigned int w = Bu[(size_t)(base + j) * 64 + f];
        acc0 += BFLO(w);
        acc1 += BFHI(w);
    }
    atomicAdd(&gsum[cur * H + 2 * f], acc0);
    atomicAdd(&gsum[cur * H + 2 * f + 1], acc1);
}

// head + pool_final fused: gv = gsum/cnt
__global__ __launch_bounds__(128) void head_kernel(const float* __restrict__ gsum,
                                                   const int* __restrict__ gstart,
                                                   const float* __restrict__ fW1,
                                                   const float* __restrict__ fb1,
                                                   const float* __restrict__ fW2,
                                                   const float* __restrict__ fb2,
                                                   float* __restrict__ out) {
    __shared__ float gv[H], hid[H], lg[DOUT];
    int gr = blockIdx.x, f = threadIdx.x;
    int cnt = gstart[gr + 1] - gstart[gr];
    gv[f] = gsum[gr * H + f] / fmaxf((float)cnt, 1.f);
    __syncthreads();
    float acc = fb1[f];
    for (int k = 0; k < H; ++k) acc = fmaf(gv[k], fW1[k * H + f], acc);
    hid[f] = fmaxf(acc, 0.f);
    __syncthreads();
    if (f < DOUT) {
        float a = fb2[f];
        for (int k = 0; k < H; ++k) a = fmaf(hid[k], fW2[k * DOUT + f], a);
        lg[f] = a;
    }
    __syncthreads();
    if (f < DOUT) {
        float mx = -1e30f;
        for (int j = 0; j < DOUT; ++j) mx = fmaxf(mx, lg[j]);
        float ssum = 0.f;
        for (int j = 0; j < DOUT; ++j) ssum += expf(lg[j] - mx);
        out[gr * DOUT + f] = expf(lg[f] - mx) / ssum;
    }
}

// ---------------- launch ----------------

extern "C" void kernel_launch(void* const* d_in, const int* in_sizes, int n_in,
                              void* d_out, int out_size, void* d_ws, size_t ws_size,
                              hipStream_t stream) {
    const float* x = (const float*)d_in[0];
    const int* edge = (const int*)d_in[1];
    const int* batch = (const int*)d_in[2];
    const float* W1 = (const float*)d_in[3];
    const float* b1 = (const float*)d_in[4];
    const float* W2 = (const float*)d_in[5];
    const float* b2 = (const float*)d_in[6];
    const float* fW1 = (const float*)d_in[7];
    const float* fb1 = (const float*)d_in[8];
    const float* fW2 = (const float*)d_in[9];
    const float* fb2 = (const float*)d_in[10];
    float* out = (float*)d_out;

    int N = in_sizes[0] / H;
    int E = in_sizes[1] / 2;
    const int* srcI = edge;
    const int* dstI = edge + E;

    char* ws = (char*)d_ws;
    size_t off = 0;
    auto alloc = [&](size_t bytes) {
        void* p = ws + off;
        off = (off + bytes + 255) & ~(size_t)255;
        return p;
    };
    int* deg = (int*)alloc((size_t)N * 4);
    int* row_ptr = (int*)alloc((size_t)(N + 1) * 4);
    int* fill = (int*)alloc((size_t)N * 4);
    int* col = (int*)alloc((size_t)E * 4);
    float* dinv = (float*)alloc((size_t)N * 4);
    int* bsum = (int*)alloc(4096);
    int* gstart = (int*)alloc(512);
    int* bcnt = (int*)alloc(NBUCK_MAX * 4);
    int* bfill = (int*)alloc(NBUCK_MAX * 4);
    unsigned int* Wbf1 = (unsigned int*)alloc(128 * 64 * 4);
    unsigned int* Wbf2 = (unsigned int*)alloc(128 * 64 * 4);
    float* gsum = (float*)alloc((size_t)NGRAPH * H * 4);
    // A region: holds es (E*8B) during CSR build, then bf16 activations (N*H*2B)
    unsigned short* Abf = (unsigned short*)alloc((size_t)N * H * 4);
    unsigned int* Bbf = (unsigned int*)alloc((size_t)N * H * 4);
    (void)ws_size;

    int2* es = (int2*)Abf;  // consumed before mm overwrites; same stream

    int bshift = 0;
    while (((N - 1) >> bshift) >= NBUCK_MAX) ++bshift;
    int nbuck = ((N - 1) >> bshift) + 1;

    hipMemsetAsync(deg, 0, (size_t)N * 4, stream);
    hipMemsetAsync(bcnt, 0, NBUCK_MAX * 4, stream);
    hipMemsetAsync(gsum, 0, (size_t)NGRAPH * H * 4, stream);

    int nb = (N + 1023) / 1024;
    int nst = (E + SORT_TILE - 1) / SORT_TILE;

    prep_w_kernel<<<32, 256, 0, stream>>>(W1, Wbf1);
    prep_w_kernel<<<32, 256, 0, stream>>>(W2, Wbf2);

    bucket_hist_kernel<<<nst, 256, 0, stream>>>(dstI, E, bshift, bcnt);
    bucket_scan_kernel<<<1, 1, 0, stream>>>(bcnt, bfill, nbuck);
    bucket_scatter_kernel<<<nst, 256, 0, stream>>>(srcI, dstI, E, bshift, bfill, es, deg);

    batch_bounds_kernel<<<(N + 255) / 256, 256, 0, stream>>>(batch, N, gstart);
    scan_phase1<<<nb, 256, 0, stream>>>(deg, N, bsum);
    scan_phase2<<<1, 1, 0, stream>>>(bsum, nb, row_ptr, N, E);
    scan_phase3<<<nb, 256, 0, stream>>>(deg, bsum, N, row_ptr, fill, dinv);
    fill_csr_sorted<<<(E + 255) / 256, 256, 0, stream>>>(es, E, fill, col);

    int mmblocks = (N + 127) / 128;
    int aggblocks = (N + 3) / 4;
    mm_mfma_kernel<0><<<mmblocks, 256, 0, stream>>>(x, Wbf1, dinv, Abf, N);
    agg_bf16_kernel<<<aggblocks, 256, 0, stream>>>((const unsigned int*)Abf, row_ptr, col,
                                                   dinv, b1, Bbf, N);
    mm_mfma_kernel<1><<<mmblocks, 256, 0, stream>>>(Bbf, Wbf2, dinv, Abf, N);
    agg_bf16_kernel<<<aggblocks, 256, 0, stream>>>((const unsigned int*)Abf, row_ptr, col,
                                                   dinv, b2, Bbf, N);
    pool_partial<<<(N + PCHUNK - 1) / PCHUNK, 64, 0, stream>>>(Bbf, batch, gsum, N);
    head_kernel<<<NGRAPH, 128, 0, stream>>>(gsum, gstart, fW1, fb1, fW2, fb2, out);
}